// Round 1
// baseline (1608.586 us; speedup 1.0000x reference)
//
#include <hip/hip_runtime.h>

#define N_NODES 100000
#define N_EDGES 3200000
#define DIM 128
#define SCAN_BLOCKS 98   // ceil(100000/1024)

// ---------------- CSR build ----------------

__global__ void hist_k(const int* __restrict__ dst, int* __restrict__ counts) {
    int i = blockIdx.x * blockDim.x + threadIdx.x;
    int stride = gridDim.x * blockDim.x;
    for (; i < N_EDGES; i += stride) atomicAdd(&counts[dst[i]], 1);
}

// block scans 1024 counts (4/thread), writes block-local exclusive scan + block total
__global__ void scan1_k(const int* __restrict__ counts, int* __restrict__ offsets,
                        int* __restrict__ blockSums) {
    __shared__ int tmp[256];
    int tid = threadIdx.x;
    int base = blockIdx.x * 1024 + tid * 4;
    int v0 = (base + 0 < N_NODES) ? counts[base + 0] : 0;
    int v1 = (base + 1 < N_NODES) ? counts[base + 1] : 0;
    int v2 = (base + 2 < N_NODES) ? counts[base + 2] : 0;
    int v3 = (base + 3 < N_NODES) ? counts[base + 3] : 0;
    int t = v0 + v1 + v2 + v3;
    tmp[tid] = t;
    __syncthreads();
    for (int off = 1; off < 256; off <<= 1) {
        int x = tmp[tid];
        if (tid >= off) x += tmp[tid - off];
        __syncthreads();
        tmp[tid] = x;
        __syncthreads();
    }
    int excl = tmp[tid] - t;  // exclusive prefix of this thread's chunk within block
    if (base + 0 < N_NODES) offsets[base + 0] = excl;
    if (base + 1 < N_NODES) offsets[base + 1] = excl + v0;
    if (base + 2 < N_NODES) offsets[base + 2] = excl + v0 + v1;
    if (base + 3 < N_NODES) offsets[base + 3] = excl + v0 + v1 + v2;
    if (tid == 255) blockSums[blockIdx.x] = tmp[255];
}

__global__ void scan2_k(const int* __restrict__ blockSums, int* __restrict__ blockOffsets) {
    __shared__ int tmp[128];
    int tid = threadIdx.x;
    int v = (tid < SCAN_BLOCKS) ? blockSums[tid] : 0;
    tmp[tid] = v;
    __syncthreads();
    for (int off = 1; off < 128; off <<= 1) {
        int x = tmp[tid];
        if (tid >= off) x += tmp[tid - off];
        __syncthreads();
        tmp[tid] = x;
        __syncthreads();
    }
    if (tid < SCAN_BLOCKS) blockOffsets[tid] = tmp[tid] - v;  // exclusive
}

__global__ void scan3_k(int* __restrict__ offsets, int* __restrict__ cursor,
                        const int* __restrict__ blockOffsets) {
    int add = blockOffsets[blockIdx.x];
    int base = blockIdx.x * 1024 + threadIdx.x * 4;
#pragma unroll
    for (int j = 0; j < 4; j++) {
        int i = base + j;
        if (i < N_NODES) {
            int o = offsets[i] + add;
            offsets[i] = o;
            cursor[i] = o;
        }
    }
    if (blockIdx.x == 0 && threadIdx.x == 0) offsets[N_NODES] = N_EDGES;
}

__global__ void fill_k(const int* __restrict__ src, const int* __restrict__ dst,
                       int* __restrict__ cursor, int* __restrict__ csr) {
    int i = blockIdx.x * blockDim.x + threadIdx.x;
    int stride = gridDim.x * blockDim.x;
    for (; i < N_EDGES; i += stride) {
        int d = dst[i];
        int p = atomicAdd(&cursor[d], 1);
        csr[p] = src[i];
    }
}

// ---------------- per-layer compute ----------------

// G[r][c] = sum_k H[r][k] * W[k][c]   (f32, vector ALU)
// block: 256 threads, 64 rows x 128 cols tile; 8 rows x 4 cols per thread
__global__ __launch_bounds__(256) void gemm_k(const float* __restrict__ H,
                                              const float* __restrict__ W,
                                              float* __restrict__ G) {
    __shared__ float hs[64][128];
    int tid = threadIdx.x;
    int rowBase = blockIdx.x * 64;
    for (int i = tid; i < 64 * 32; i += 256) {
        int r = i >> 5, c4 = i & 31;
        int row = rowBase + r;
        float4 v = make_float4(0.f, 0.f, 0.f, 0.f);
        if (row < N_NODES) v = ((const float4*)(H + (size_t)row * DIM))[c4];
        ((float4*)&hs[r][0])[c4] = v;
    }
    __syncthreads();

    int tx = tid & 31, ty = tid >> 5;
    int c0 = tx * 4, r0 = ty * 8;
    float4 acc[8];
#pragma unroll
    for (int r = 0; r < 8; r++) acc[r] = make_float4(0.f, 0.f, 0.f, 0.f);

#pragma unroll 4
    for (int k = 0; k < DIM; k++) {
        float4 wv = *(const float4*)(W + (size_t)k * DIM + c0);
#pragma unroll
        for (int r = 0; r < 8; r++) {
            float a = hs[r0 + r][k];
            acc[r].x += a * wv.x;
            acc[r].y += a * wv.y;
            acc[r].z += a * wv.z;
            acc[r].w += a * wv.w;
        }
    }
#pragma unroll
    for (int r = 0; r < 8; r++) {
        int row = rowBase + r0 + r;
        if (row < N_NODES) *(float4*)(G + (size_t)row * DIM + c0) = acc[r];
    }
}

// out[i] = (1+eps)*G[i] + sum_{e in-edges of i} G[csr[e]] + b
// one wave (64 lanes) per node, float2 per lane = 512B coalesced rows
__global__ __launch_bounds__(256) void agg_k(const float* __restrict__ G,
                                             const int* __restrict__ off,
                                             const int* __restrict__ csr,
                                             const float* __restrict__ bias,
                                             const float* __restrict__ epsp,
                                             float* __restrict__ out) {
    int lane = threadIdx.x & 63;
    int node = blockIdx.x * 4 + (threadIdx.x >> 6);
    if (node >= N_NODES) return;
    float e1 = 1.0f + epsp[0];
    const float2* G2 = (const float2*)G;
    float2 bb = ((const float2*)bias)[lane];
    float2 self = G2[(size_t)node * 64 + lane];
    float ax = bb.x + e1 * self.x;
    float ay = bb.y + e1 * self.y;
    int s = off[node], e = off[node + 1];
    for (int i = s; i < e; i++) {
        int sn = csr[i];
        float2 v = G2[(size_t)sn * 64 + lane];
        ax += v.x;
        ay += v.y;
    }
    ((float2*)out)[(size_t)node * 64 + lane] = make_float2(ax, ay);
}

// ---------------- launch ----------------

extern "C" void kernel_launch(void* const* d_in, const int* in_sizes, int n_in,
                              void* d_out, int out_size, void* d_ws, size_t ws_size,
                              hipStream_t stream) {
    const float* feats = (const float*)d_in[0];
    const int* esrc = (const int*)d_in[1];
    const int* edst = (const int*)d_in[2];
    const float* Wm[3] = {(const float*)d_in[3], (const float*)d_in[6], (const float*)d_in[9]};
    const float* Bv[3] = {(const float*)d_in[4], (const float*)d_in[7], (const float*)d_in[10]};
    const float* Ev[3] = {(const float*)d_in[5], (const float*)d_in[8], (const float*)d_in[11]};
    float* out = (float*)d_out;

    char* ws = (char*)d_ws;
    float* bufA  = (float*)(ws);                  // 51,200,000 B : g = h @ W
    int* csr     = (int*)(ws + 51200000);         // 12,800,000 B
    int* counts  = (int*)(ws + 64000000);         //    400,000 B
    int* offsets = (int*)(ws + 64400128);         //    400,004 B
    int* cursor  = (int*)(ws + 64800384);         //    400,000 B
    int* bsums   = (int*)(ws + 65200640);         //        392 B
    int* boffs   = (int*)(ws + 65201152);         //        392 B

    // CSR build (once per launch; ws is re-poisoned so rebuild every call)
    hipMemsetAsync(counts, 0, N_NODES * sizeof(int), stream);
    hist_k<<<2048, 256, 0, stream>>>(edst, counts);
    scan1_k<<<SCAN_BLOCKS, 256, 0, stream>>>(counts, offsets, bsums);
    scan2_k<<<1, 128, 0, stream>>>(bsums, boffs);
    scan3_k<<<SCAN_BLOCKS, 256, 0, stream>>>(offsets, cursor, boffs);
    fill_k<<<2048, 256, 0, stream>>>(esrc, edst, cursor, csr);

    // 3 GIN layers: g = h @ W  (bufA);  h' = (1+eps)g + agg(g) + b  (d_out)
    const float* h = feats;
    for (int l = 0; l < 3; l++) {
        gemm_k<<<(N_NODES + 63) / 64, 256, 0, stream>>>(h, Wm[l], bufA);
        agg_k<<<N_NODES / 4, 256, 0, stream>>>(bufA, offsets, csr, Bv[l], Ev[l], out);
        h = out;
    }
}

// Round 2
// 1216.132 us; speedup vs baseline: 1.3227x; 1.3227x over previous
//
#include <hip/hip_runtime.h>

#define N_NODES 100000
#define N_EDGES 3200000
#define DIM 128
#define SCAN_BLOCKS 98   // ceil(100000/1024)

// ---------------- CSR build ----------------

__global__ void hist_k(const int* __restrict__ dst, int* __restrict__ counts) {
    int i = blockIdx.x * blockDim.x + threadIdx.x;
    int stride = gridDim.x * blockDim.x;
    for (; i < N_EDGES; i += stride) atomicAdd(&counts[dst[i]], 1);
}

// block scans 1024 counts (4/thread), writes block-local exclusive scan + block total
__global__ void scan1_k(const int* __restrict__ counts, int* __restrict__ offsets,
                        int* __restrict__ blockSums) {
    __shared__ int tmp[256];
    int tid = threadIdx.x;
    int base = blockIdx.x * 1024 + tid * 4;
    int v0 = (base + 0 < N_NODES) ? counts[base + 0] : 0;
    int v1 = (base + 1 < N_NODES) ? counts[base + 1] : 0;
    int v2 = (base + 2 < N_NODES) ? counts[base + 2] : 0;
    int v3 = (base + 3 < N_NODES) ? counts[base + 3] : 0;
    int t = v0 + v1 + v2 + v3;
    tmp[tid] = t;
    __syncthreads();
    for (int off = 1; off < 256; off <<= 1) {
        int x = tmp[tid];
        if (tid >= off) x += tmp[tid - off];
        __syncthreads();
        tmp[tid] = x;
        __syncthreads();
    }
    int excl = tmp[tid] - t;  // exclusive prefix of this thread's chunk within block
    if (base + 0 < N_NODES) offsets[base + 0] = excl;
    if (base + 1 < N_NODES) offsets[base + 1] = excl + v0;
    if (base + 2 < N_NODES) offsets[base + 2] = excl + v0 + v1;
    if (base + 3 < N_NODES) offsets[base + 3] = excl + v0 + v1 + v2;
    if (tid == 255) blockSums[blockIdx.x] = tmp[255];
}

__global__ void scan2_k(const int* __restrict__ blockSums, int* __restrict__ blockOffsets) {
    __shared__ int tmp[128];
    int tid = threadIdx.x;
    int v = (tid < SCAN_BLOCKS) ? blockSums[tid] : 0;
    tmp[tid] = v;
    __syncthreads();
    for (int off = 1; off < 128; off <<= 1) {
        int x = tmp[tid];
        if (tid >= off) x += tmp[tid - off];
        __syncthreads();
        tmp[tid] = x;
        __syncthreads();
    }
    if (tid < SCAN_BLOCKS) blockOffsets[tid] = tmp[tid] - v;  // exclusive
}

__global__ void scan3_k(int* __restrict__ offsets, int* __restrict__ cursor,
                        const int* __restrict__ blockOffsets) {
    int add = blockOffsets[blockIdx.x];
    int base = blockIdx.x * 1024 + threadIdx.x * 4;
#pragma unroll
    for (int j = 0; j < 4; j++) {
        int i = base + j;
        if (i < N_NODES) {
            int o = offsets[i] + add;
            offsets[i] = o;
            cursor[i] = o;
        }
    }
    if (blockIdx.x == 0 && threadIdx.x == 0) offsets[N_NODES] = N_EDGES;
}

__global__ void fill_k(const int* __restrict__ src, const int* __restrict__ dst,
                       int* __restrict__ cursor, int* __restrict__ csr) {
    int i = blockIdx.x * blockDim.x + threadIdx.x;
    int stride = gridDim.x * blockDim.x;
    for (; i < N_EDGES; i += stride) {
        int d = dst[i];
        int p = atomicAdd(&cursor[d], 1);
        csr[p] = src[i];
    }
}

// ---------------- per-layer compute ----------------

// G[r][c] = sum_k H[r][k] * W[k][c]   (f32, vector ALU)
// block: 256 threads, 64 rows x 128 cols tile; 8 rows x 4 cols per thread
__global__ __launch_bounds__(256) void gemm_k(const float* __restrict__ H,
                                              const float* __restrict__ W,
                                              float* __restrict__ G) {
    __shared__ float hs[64][128];
    int tid = threadIdx.x;
    int rowBase = blockIdx.x * 64;
    for (int i = tid; i < 64 * 32; i += 256) {
        int r = i >> 5, c4 = i & 31;
        int row = rowBase + r;
        float4 v = make_float4(0.f, 0.f, 0.f, 0.f);
        if (row < N_NODES) v = ((const float4*)(H + (size_t)row * DIM))[c4];
        ((float4*)&hs[r][0])[c4] = v;
    }
    __syncthreads();

    int tx = tid & 31, ty = tid >> 5;
    int c0 = tx * 4, r0 = ty * 8;
    float4 acc[8];
#pragma unroll
    for (int r = 0; r < 8; r++) acc[r] = make_float4(0.f, 0.f, 0.f, 0.f);

#pragma unroll 4
    for (int k = 0; k < DIM; k++) {
        float4 wv = *(const float4*)(W + (size_t)k * DIM + c0);
#pragma unroll
        for (int r = 0; r < 8; r++) {
            float a = hs[r0 + r][k];
            acc[r].x += a * wv.x;
            acc[r].y += a * wv.y;
            acc[r].z += a * wv.z;
            acc[r].w += a * wv.w;
        }
    }
#pragma unroll
    for (int r = 0; r < 8; r++) {
        int row = rowBase + r0 + r;
        if (row < N_NODES) *(float4*)(G + (size_t)row * DIM + c0) = acc[r];
    }
}

// out[i] = (1+eps)*G[i] + sum_{e in-edges of i} G[csr[e]] + b
// one wave (64 lanes) per node, float2 per lane = 512B coalesced rows.
// Edge loop unrolled x8: 8 independent row-gathers in flight per wave (4KB)
// to fix MLP starvation (round-1: VALUBusy 12.8%, 34% HBM, latency-bound).
__global__ __launch_bounds__(256) void agg_k(const float* __restrict__ G,
                                             const int* __restrict__ off,
                                             const int* __restrict__ csr,
                                             const float* __restrict__ bias,
                                             const float* __restrict__ epsp,
                                             float* __restrict__ out) {
    int lane = threadIdx.x & 63;
    int node = blockIdx.x * 4 + (threadIdx.x >> 6);
    if (node >= N_NODES) return;
    float e1 = 1.0f + epsp[0];
    const float2* G2 = (const float2*)G;
    float2 bb = ((const float2*)bias)[lane];
    float2 self = G2[(size_t)node * 64 + lane];
    float ax = bb.x + e1 * self.x;
    float ay = bb.y + e1 * self.y;
    int s = off[node], e = off[node + 1];
    int i = s;
    for (; i + 8 <= e; i += 8) {
        int n0 = csr[i + 0];
        int n1 = csr[i + 1];
        int n2 = csr[i + 2];
        int n3 = csr[i + 3];
        int n4 = csr[i + 4];
        int n5 = csr[i + 5];
        int n6 = csr[i + 6];
        int n7 = csr[i + 7];
        float2 v0 = G2[(size_t)n0 * 64 + lane];
        float2 v1 = G2[(size_t)n1 * 64 + lane];
        float2 v2 = G2[(size_t)n2 * 64 + lane];
        float2 v3 = G2[(size_t)n3 * 64 + lane];
        float2 v4 = G2[(size_t)n4 * 64 + lane];
        float2 v5 = G2[(size_t)n5 * 64 + lane];
        float2 v6 = G2[(size_t)n6 * 64 + lane];
        float2 v7 = G2[(size_t)n7 * 64 + lane];
        ax += ((v0.x + v1.x) + (v2.x + v3.x)) + ((v4.x + v5.x) + (v6.x + v7.x));
        ay += ((v0.y + v1.y) + (v2.y + v3.y)) + ((v4.y + v5.y) + (v6.y + v7.y));
    }
    for (; i < e; i++) {
        int sn = csr[i];
        float2 v = G2[(size_t)sn * 64 + lane];
        ax += v.x;
        ay += v.y;
    }
    ((float2*)out)[(size_t)node * 64 + lane] = make_float2(ax, ay);
}

// ---------------- launch ----------------

extern "C" void kernel_launch(void* const* d_in, const int* in_sizes, int n_in,
                              void* d_out, int out_size, void* d_ws, size_t ws_size,
                              hipStream_t stream) {
    const float* feats = (const float*)d_in[0];
    const int* esrc = (const int*)d_in[1];
    const int* edst = (const int*)d_in[2];
    const float* Wm[3] = {(const float*)d_in[3], (const float*)d_in[6], (const float*)d_in[9]};
    const float* Bv[3] = {(const float*)d_in[4], (const float*)d_in[7], (const float*)d_in[10]};
    const float* Ev[3] = {(const float*)d_in[5], (const float*)d_in[8], (const float*)d_in[11]};
    float* out = (float*)d_out;

    char* ws = (char*)d_ws;
    float* bufA  = (float*)(ws);                  // 51,200,000 B : g = h @ W
    int* csr     = (int*)(ws + 51200000);         // 12,800,000 B
    int* counts  = (int*)(ws + 64000000);         //    400,000 B
    int* offsets = (int*)(ws + 64400128);         //    400,004 B
    int* cursor  = (int*)(ws + 64800384);         //    400,000 B
    int* bsums   = (int*)(ws + 65200640);         //        392 B
    int* boffs   = (int*)(ws + 65201152);         //        392 B

    // CSR build (once per launch; ws is re-poisoned so rebuild every call)
    hipMemsetAsync(counts, 0, N_NODES * sizeof(int), stream);
    hist_k<<<2048, 256, 0, stream>>>(edst, counts);
    scan1_k<<<SCAN_BLOCKS, 256, 0, stream>>>(counts, offsets, bsums);
    scan2_k<<<1, 128, 0, stream>>>(bsums, boffs);
    scan3_k<<<SCAN_BLOCKS, 256, 0, stream>>>(offsets, cursor, boffs);
    fill_k<<<2048, 256, 0, stream>>>(esrc, edst, cursor, csr);

    // 3 GIN layers: g = h @ W  (bufA);  h' = (1+eps)g + agg(g) + b  (d_out)
    const float* h = feats;
    for (int l = 0; l < 3; l++) {
        gemm_k<<<(N_NODES + 63) / 64, 256, 0, stream>>>(h, Wm[l], bufA);
        agg_k<<<N_NODES / 4, 256, 0, stream>>>(bufA, offsets, csr, Bv[l], Ev[l], out);
        h = out;
    }
}

// Round 3
// 1138.780 us; speedup vs baseline: 1.4126x; 1.0679x over previous
//
#include <hip/hip_runtime.h>

#define N_NODES 100000
#define N_EDGES 3200000
#define DIM 128
#define SCAN_BLOCKS 98   // ceil(100000/1024)

// ---------------- CSR build (rank-based, single atomic pass) ----------------

// rank[i] = arrival order of edge i within its dst bucket; counts[d] ends as degree(d).
// 4 edges/thread: int4-coalesced loads, 4 independent atomics in flight, int4 store.
__global__ __launch_bounds__(256) void rank_k(const int* __restrict__ dst,
                                              int* __restrict__ counts,
                                              int* __restrict__ rank) {
    int t = blockIdx.x * blockDim.x + threadIdx.x;   // 800,000 threads, 4 edges each
    int4 d4 = ((const int4*)dst)[t];
    int r0 = atomicAdd(&counts[d4.x], 1);
    int r1 = atomicAdd(&counts[d4.y], 1);
    int r2 = atomicAdd(&counts[d4.z], 1);
    int r3 = atomicAdd(&counts[d4.w], 1);
    ((int4*)rank)[t] = make_int4(r0, r1, r2, r3);
}

// csr[offsets[dst[i]] + rank[i]] = src[i]  -- no atomics, stores fire-and-forget
__global__ __launch_bounds__(256) void place_k(const int* __restrict__ src,
                                               const int* __restrict__ dst,
                                               const int* __restrict__ rank,
                                               const int* __restrict__ offsets,
                                               int* __restrict__ csr) {
    int t = blockIdx.x * blockDim.x + threadIdx.x;
    int4 d4 = ((const int4*)dst)[t];
    int4 r4 = ((const int4*)rank)[t];
    int4 s4 = ((const int4*)src)[t];
    int o0 = offsets[d4.x];
    int o1 = offsets[d4.y];
    int o2 = offsets[d4.z];
    int o3 = offsets[d4.w];
    csr[o0 + r4.x] = s4.x;
    csr[o1 + r4.y] = s4.y;
    csr[o2 + r4.z] = s4.z;
    csr[o3 + r4.w] = s4.w;
}

// block scans 1024 counts (4/thread), writes block-local exclusive scan + block total
__global__ void scan1_k(const int* __restrict__ counts, int* __restrict__ offsets,
                        int* __restrict__ blockSums) {
    __shared__ int tmp[256];
    int tid = threadIdx.x;
    int base = blockIdx.x * 1024 + tid * 4;
    int v0 = (base + 0 < N_NODES) ? counts[base + 0] : 0;
    int v1 = (base + 1 < N_NODES) ? counts[base + 1] : 0;
    int v2 = (base + 2 < N_NODES) ? counts[base + 2] : 0;
    int v3 = (base + 3 < N_NODES) ? counts[base + 3] : 0;
    int t = v0 + v1 + v2 + v3;
    tmp[tid] = t;
    __syncthreads();
    for (int off = 1; off < 256; off <<= 1) {
        int x = tmp[tid];
        if (tid >= off) x += tmp[tid - off];
        __syncthreads();
        tmp[tid] = x;
        __syncthreads();
    }
    int excl = tmp[tid] - t;
    if (base + 0 < N_NODES) offsets[base + 0] = excl;
    if (base + 1 < N_NODES) offsets[base + 1] = excl + v0;
    if (base + 2 < N_NODES) offsets[base + 2] = excl + v0 + v1;
    if (base + 3 < N_NODES) offsets[base + 3] = excl + v0 + v1 + v2;
    if (tid == 255) blockSums[blockIdx.x] = tmp[255];
}

__global__ void scan2_k(const int* __restrict__ blockSums, int* __restrict__ blockOffsets) {
    __shared__ int tmp[128];
    int tid = threadIdx.x;
    int v = (tid < SCAN_BLOCKS) ? blockSums[tid] : 0;
    tmp[tid] = v;
    __syncthreads();
    for (int off = 1; off < 128; off <<= 1) {
        int x = tmp[tid];
        if (tid >= off) x += tmp[tid - off];
        __syncthreads();
        tmp[tid] = x;
        __syncthreads();
    }
    if (tid < SCAN_BLOCKS) blockOffsets[tid] = tmp[tid] - v;
}

__global__ void scan3_k(int* __restrict__ offsets, const int* __restrict__ blockOffsets) {
    int add = blockOffsets[blockIdx.x];
    int base = blockIdx.x * 1024 + threadIdx.x * 4;
#pragma unroll
    for (int j = 0; j < 4; j++) {
        int i = base + j;
        if (i < N_NODES) offsets[i] += add;
    }
    if (blockIdx.x == 0 && threadIdx.x == 0) offsets[N_NODES] = N_EDGES;
}

// ---------------- per-layer compute ----------------

// G[r][c] = sum_k H[r][k] * W[k][c]   (f32, vector ALU)
__global__ __launch_bounds__(256) void gemm_k(const float* __restrict__ H,
                                              const float* __restrict__ W,
                                              float* __restrict__ G) {
    __shared__ float hs[64][128];
    int tid = threadIdx.x;
    int rowBase = blockIdx.x * 64;
    for (int i = tid; i < 64 * 32; i += 256) {
        int r = i >> 5, c4 = i & 31;
        int row = rowBase + r;
        float4 v = make_float4(0.f, 0.f, 0.f, 0.f);
        if (row < N_NODES) v = ((const float4*)(H + (size_t)row * DIM))[c4];
        ((float4*)&hs[r][0])[c4] = v;
    }
    __syncthreads();

    int tx = tid & 31, ty = tid >> 5;
    int c0 = tx * 4, r0 = ty * 8;
    float4 acc[8];
#pragma unroll
    for (int r = 0; r < 8; r++) acc[r] = make_float4(0.f, 0.f, 0.f, 0.f);

#pragma unroll 4
    for (int k = 0; k < DIM; k++) {
        float4 wv = *(const float4*)(W + (size_t)k * DIM + c0);
#pragma unroll
        for (int r = 0; r < 8; r++) {
            float a = hs[r0 + r][k];
            acc[r].x += a * wv.x;
            acc[r].y += a * wv.y;
            acc[r].z += a * wv.z;
            acc[r].w += a * wv.w;
        }
    }
#pragma unroll
    for (int r = 0; r < 8; r++) {
        int row = rowBase + r0 + r;
        if (row < N_NODES) *(float4*)(G + (size_t)row * DIM + c0) = acc[r];
    }
}

// out[i] = (1+eps)*G[i] + sum_{e in-edges of i} G[csr[e]] + b
// one wave per node, float2/lane; edge loop unrolled x8 (8 gathers in flight)
__global__ __launch_bounds__(256) void agg_k(const float* __restrict__ G,
                                             const int* __restrict__ off,
                                             const int* __restrict__ csr,
                                             const float* __restrict__ bias,
                                             const float* __restrict__ epsp,
                                             float* __restrict__ out) {
    int lane = threadIdx.x & 63;
    int node = blockIdx.x * 4 + (threadIdx.x >> 6);
    if (node >= N_NODES) return;
    float e1 = 1.0f + epsp[0];
    const float2* G2 = (const float2*)G;
    float2 bb = ((const float2*)bias)[lane];
    float2 self = G2[(size_t)node * 64 + lane];
    float ax = bb.x + e1 * self.x;
    float ay = bb.y + e1 * self.y;
    int s = off[node], e = off[node + 1];
    int i = s;
    for (; i + 8 <= e; i += 8) {
        int n0 = csr[i + 0];
        int n1 = csr[i + 1];
        int n2 = csr[i + 2];
        int n3 = csr[i + 3];
        int n4 = csr[i + 4];
        int n5 = csr[i + 5];
        int n6 = csr[i + 6];
        int n7 = csr[i + 7];
        float2 v0 = G2[(size_t)n0 * 64 + lane];
        float2 v1 = G2[(size_t)n1 * 64 + lane];
        float2 v2 = G2[(size_t)n2 * 64 + lane];
        float2 v3 = G2[(size_t)n3 * 64 + lane];
        float2 v4 = G2[(size_t)n4 * 64 + lane];
        float2 v5 = G2[(size_t)n5 * 64 + lane];
        float2 v6 = G2[(size_t)n6 * 64 + lane];
        float2 v7 = G2[(size_t)n7 * 64 + lane];
        ax += ((v0.x + v1.x) + (v2.x + v3.x)) + ((v4.x + v5.x) + (v6.x + v7.x));
        ay += ((v0.y + v1.y) + (v2.y + v3.y)) + ((v4.y + v5.y) + (v6.y + v7.y));
    }
    for (; i < e; i++) {
        int sn = csr[i];
        float2 v = G2[(size_t)sn * 64 + lane];
        ax += v.x;
        ay += v.y;
    }
    ((float2*)out)[(size_t)node * 64 + lane] = make_float2(ax, ay);
}

// ---------------- launch ----------------

extern "C" void kernel_launch(void* const* d_in, const int* in_sizes, int n_in,
                              void* d_out, int out_size, void* d_ws, size_t ws_size,
                              hipStream_t stream) {
    const float* feats = (const float*)d_in[0];
    const int* esrc = (const int*)d_in[1];
    const int* edst = (const int*)d_in[2];
    const float* Wm[3] = {(const float*)d_in[3], (const float*)d_in[6], (const float*)d_in[9]};
    const float* Bv[3] = {(const float*)d_in[4], (const float*)d_in[7], (const float*)d_in[10]};
    const float* Ev[3] = {(const float*)d_in[5], (const float*)d_in[8], (const float*)d_in[11]};
    float* out = (float*)d_out;

    char* ws = (char*)d_ws;
    float* bufA  = (float*)(ws);                  // 51,200,000 B : g = h @ W
    int* csr     = (int*)(ws + 51200000);         // 12,800,000 B
    int* rankb   = (int*)(ws + 64000000);         // 12,800,000 B
    int* counts  = (int*)(ws + 76800000);         //    400,000 B
    int* offsets = (int*)(ws + 77200128);         //    400,004 B
    int* bsums   = (int*)(ws + 77600384);         //        392 B
    int* boffs   = (int*)(ws + 77600896);         //        392 B

    // CSR build: one atomic pass (rank), scan, then atomic-free placement
    hipMemsetAsync(counts, 0, N_NODES * sizeof(int), stream);
    rank_k<<<N_EDGES / 1024, 256, 0, stream>>>(edst, counts, rankb);
    scan1_k<<<SCAN_BLOCKS, 256, 0, stream>>>(counts, offsets, bsums);
    scan2_k<<<1, 128, 0, stream>>>(bsums, boffs);
    scan3_k<<<SCAN_BLOCKS, 256, 0, stream>>>(offsets, boffs);
    place_k<<<N_EDGES / 1024, 256, 0, stream>>>(esrc, edst, rankb, offsets, csr);

    // 3 GIN layers: g = h @ W  (bufA);  h' = (1+eps)g + agg(g) + b  (d_out)
    const float* h = feats;
    for (int l = 0; l < 3; l++) {
        gemm_k<<<(N_NODES + 63) / 64, 256, 0, stream>>>(h, Wm[l], bufA);
        agg_k<<<N_NODES / 4, 256, 0, stream>>>(bufA, offsets, csr, Bv[l], Ev[l], out);
        h = out;
    }
}

// Round 4
// 822.797 us; speedup vs baseline: 1.9550x; 1.3840x over previous
//
#include <hip/hip_runtime.h>

#define N_NODES 100000
#define N_EDGES 3200000
#define DIM 128
#define SCAN_BLOCKS 98   // ceil(100000/1024)

// ---------------- helpers ----------------

__device__ __forceinline__ unsigned rne_bf16(float f) {
    unsigned u = __builtin_bit_cast(unsigned, f);
    return (u + 0x7FFFu + ((u >> 16) & 1u)) >> 16;
}
__device__ __forceinline__ float bf16lo(unsigned u) {        // element at lower addr
    return __builtin_bit_cast(float, u << 16);
}
__device__ __forceinline__ float bf16hi(unsigned u) {
    return __builtin_bit_cast(float, u & 0xFFFF0000u);
}

// ---------------- CSR build (rank-based, single atomic pass) ----------------

__global__ __launch_bounds__(256) void rank_k(const int* __restrict__ dst,
                                              int* __restrict__ counts,
                                              int* __restrict__ rank) {
    int t = blockIdx.x * blockDim.x + threadIdx.x;   // 800,000 threads, 4 edges each
    int4 d4 = ((const int4*)dst)[t];
    int r0 = atomicAdd(&counts[d4.x], 1);
    int r1 = atomicAdd(&counts[d4.y], 1);
    int r2 = atomicAdd(&counts[d4.z], 1);
    int r3 = atomicAdd(&counts[d4.w], 1);
    ((int4*)rank)[t] = make_int4(r0, r1, r2, r3);
}

__global__ __launch_bounds__(256) void place_k(const int* __restrict__ src,
                                               const int* __restrict__ dst,
                                               const int* __restrict__ rank,
                                               const int* __restrict__ offsets,
                                               int* __restrict__ csr) {
    int t = blockIdx.x * blockDim.x + threadIdx.x;
    int4 d4 = ((const int4*)dst)[t];
    int4 r4 = ((const int4*)rank)[t];
    int4 s4 = ((const int4*)src)[t];
    int o0 = offsets[d4.x];
    int o1 = offsets[d4.y];
    int o2 = offsets[d4.z];
    int o3 = offsets[d4.w];
    csr[o0 + r4.x] = s4.x;
    csr[o1 + r4.y] = s4.y;
    csr[o2 + r4.z] = s4.z;
    csr[o3 + r4.w] = s4.w;
}

__global__ void scan1_k(const int* __restrict__ counts, int* __restrict__ offsets,
                        int* __restrict__ blockSums) {
    __shared__ int tmp[256];
    int tid = threadIdx.x;
    int base = blockIdx.x * 1024 + tid * 4;
    int v0 = (base + 0 < N_NODES) ? counts[base + 0] : 0;
    int v1 = (base + 1 < N_NODES) ? counts[base + 1] : 0;
    int v2 = (base + 2 < N_NODES) ? counts[base + 2] : 0;
    int v3 = (base + 3 < N_NODES) ? counts[base + 3] : 0;
    int t = v0 + v1 + v2 + v3;
    tmp[tid] = t;
    __syncthreads();
    for (int off = 1; off < 256; off <<= 1) {
        int x = tmp[tid];
        if (tid >= off) x += tmp[tid - off];
        __syncthreads();
        tmp[tid] = x;
        __syncthreads();
    }
    int excl = tmp[tid] - t;
    if (base + 0 < N_NODES) offsets[base + 0] = excl;
    if (base + 1 < N_NODES) offsets[base + 1] = excl + v0;
    if (base + 2 < N_NODES) offsets[base + 2] = excl + v0 + v1;
    if (base + 3 < N_NODES) offsets[base + 3] = excl + v0 + v1 + v2;
    if (tid == 255) blockSums[blockIdx.x] = tmp[255];
}

__global__ void scan2_k(const int* __restrict__ blockSums, int* __restrict__ blockOffsets) {
    __shared__ int tmp[128];
    int tid = threadIdx.x;
    int v = (tid < SCAN_BLOCKS) ? blockSums[tid] : 0;
    tmp[tid] = v;
    __syncthreads();
    for (int off = 1; off < 128; off <<= 1) {
        int x = tmp[tid];
        if (tid >= off) x += tmp[tid - off];
        __syncthreads();
        tmp[tid] = x;
        __syncthreads();
    }
    if (tid < SCAN_BLOCKS) blockOffsets[tid] = tmp[tid] - v;
}

__global__ void scan3_k(int* __restrict__ offsets, const int* __restrict__ blockOffsets) {
    int add = blockOffsets[blockIdx.x];
    int base = blockIdx.x * 1024 + threadIdx.x * 4;
#pragma unroll
    for (int j = 0; j < 4; j++) {
        int i = base + j;
        if (i < N_NODES) offsets[i] += add;
    }
    if (blockIdx.x == 0 && threadIdx.x == 0) offsets[N_NODES] = N_EDGES;
}

// ---------------- per-layer compute ----------------

// G[r][c] = sum_k H[r][k] * W[k][c]; output stored as bf16 (RNE) for the gather
__global__ __launch_bounds__(256) void gemm_k(const float* __restrict__ H,
                                              const float* __restrict__ W,
                                              unsigned short* __restrict__ G) {
    __shared__ float hs[64][128];
    int tid = threadIdx.x;
    int rowBase = blockIdx.x * 64;
    for (int i = tid; i < 64 * 32; i += 256) {
        int r = i >> 5, c4 = i & 31;
        int row = rowBase + r;
        float4 v = make_float4(0.f, 0.f, 0.f, 0.f);
        if (row < N_NODES) v = ((const float4*)(H + (size_t)row * DIM))[c4];
        ((float4*)&hs[r][0])[c4] = v;
    }
    __syncthreads();

    int tx = tid & 31, ty = tid >> 5;
    int c0 = tx * 4, r0 = ty * 8;
    float4 acc[8];
#pragma unroll
    for (int r = 0; r < 8; r++) acc[r] = make_float4(0.f, 0.f, 0.f, 0.f);

#pragma unroll 4
    for (int k = 0; k < DIM; k++) {
        float4 wv = *(const float4*)(W + (size_t)k * DIM + c0);
#pragma unroll
        for (int r = 0; r < 8; r++) {
            float a = hs[r0 + r][k];
            acc[r].x += a * wv.x;
            acc[r].y += a * wv.y;
            acc[r].z += a * wv.z;
            acc[r].w += a * wv.w;
        }
    }
#pragma unroll
    for (int r = 0; r < 8; r++) {
        int row = rowBase + r0 + r;
        if (row < N_NODES) {
            uint2 pk;
            pk.x = rne_bf16(acc[r].x) | (rne_bf16(acc[r].y) << 16);
            pk.y = rne_bf16(acc[r].z) | (rne_bf16(acc[r].w) << 16);
            *(uint2*)(G + (size_t)row * DIM + c0) = pk;
        }
    }
}

// out[i] = (1+eps)*G[i] + sum_{in-edges} G[csr[e]] + b   (G in bf16, out f32)
// One wave per node. Pair-gather: one uint2/lane instr = 512B = TWO bf16 rows
// (lanes 0-31 = edge A, lanes 32-63 = edge B); halves combined by shfl_xor(32).
// 8 pairs (16 edges) in flight = 4KB/wave.
__global__ __launch_bounds__(256) void agg_k(const unsigned short* __restrict__ G,
                                             const int* __restrict__ off,
                                             const int* __restrict__ csr,
                                             const float* __restrict__ bias,
                                             const float* __restrict__ epsp,
                                             float* __restrict__ out) {
    int lane = threadIdx.x & 63;
    int node = blockIdx.x * 4 + (threadIdx.x >> 6);   // grid covers exactly N_NODES
    int half = lane >> 5;
    int q = lane & 31;                                 // this lane covers cols 4q..4q+3
    float e1 = 1.0f + epsp[0];

    float4 acc = make_float4(0.f, 0.f, 0.f, 0.f);
    int s = off[node], e = off[node + 1];
    int n = e - s;
    const int* cl = csr + s;
    int i = 0;
    for (; i + 16 <= n; i += 16) {
        uint2 v[8];
#pragma unroll
        for (int p = 0; p < 8; p++) {
            int idx = cl[i + 2 * p + half];
            v[p] = *(const uint2*)(G + (size_t)idx * DIM + q * 4);
        }
#pragma unroll
        for (int p = 0; p < 8; p++) {
            acc.x += bf16lo(v[p].x);
            acc.y += bf16hi(v[p].x);
            acc.z += bf16lo(v[p].y);
            acc.w += bf16hi(v[p].y);
        }
    }
    for (; i + 2 <= n; i += 2) {
        int idx = cl[i + half];
        uint2 v = *(const uint2*)(G + (size_t)idx * DIM + q * 4);
        acc.x += bf16lo(v.x);
        acc.y += bf16hi(v.x);
        acc.z += bf16lo(v.y);
        acc.w += bf16hi(v.y);
    }
    if (i < n) {  // odd tail: both halves load same row, only half A accumulates
        int idx = cl[n - 1];
        uint2 v = *(const uint2*)(G + (size_t)idx * DIM + q * 4);
        if (half == 0) {
            acc.x += bf16lo(v.x);
            acc.y += bf16hi(v.x);
            acc.z += bf16lo(v.y);
            acc.w += bf16hi(v.y);
        }
    }
    // combine edge-slot halves
    acc.x += __shfl_xor(acc.x, 32);
    acc.y += __shfl_xor(acc.y, 32);
    acc.z += __shfl_xor(acc.z, 32);
    acc.w += __shfl_xor(acc.w, 32);

    if (half == 0) {
        uint2 sv = *(const uint2*)(G + (size_t)node * DIM + q * 4);
        float4 bb = *(const float4*)(bias + q * 4);
        float4 r;
        r.x = acc.x + e1 * bf16lo(sv.x) + bb.x;
        r.y = acc.y + e1 * bf16hi(sv.x) + bb.y;
        r.z = acc.z + e1 * bf16lo(sv.y) + bb.z;
        r.w = acc.w + e1 * bf16hi(sv.y) + bb.w;
        *(float4*)(out + (size_t)node * DIM + q * 4) = r;
    }
}

// ---------------- launch ----------------

extern "C" void kernel_launch(void* const* d_in, const int* in_sizes, int n_in,
                              void* d_out, int out_size, void* d_ws, size_t ws_size,
                              hipStream_t stream) {
    const float* feats = (const float*)d_in[0];
    const int* esrc = (const int*)d_in[1];
    const int* edst = (const int*)d_in[2];
    const float* Wm[3] = {(const float*)d_in[3], (const float*)d_in[6], (const float*)d_in[9]};
    const float* Bv[3] = {(const float*)d_in[4], (const float*)d_in[7], (const float*)d_in[10]};
    const float* Ev[3] = {(const float*)d_in[5], (const float*)d_in[8], (const float*)d_in[11]};
    float* out = (float*)d_out;

    char* ws = (char*)d_ws;
    unsigned short* bufG = (unsigned short*)(ws);     // 25,600,000 B : g = h @ W (bf16)
    int* csr     = (int*)(ws + 25600000);             // 12,800,000 B
    int* rankb   = (int*)(ws + 38400000);             // 12,800,000 B
    int* counts  = (int*)(ws + 51200000);             //    400,000 B
    int* offsets = (int*)(ws + 51600128);             //    400,004 B
    int* bsums   = (int*)(ws + 52000384);             //        392 B
    int* boffs   = (int*)(ws + 52000896);             //        392 B

    // CSR build: one atomic pass (rank), scan, then atomic-free placement
    hipMemsetAsync(counts, 0, N_NODES * sizeof(int), stream);
    rank_k<<<N_EDGES / 1024, 256, 0, stream>>>(edst, counts, rankb);
    scan1_k<<<SCAN_BLOCKS, 256, 0, stream>>>(counts, offsets, bsums);
    scan2_k<<<1, 128, 0, stream>>>(bsums, boffs);
    scan3_k<<<SCAN_BLOCKS, 256, 0, stream>>>(offsets, boffs);
    place_k<<<N_EDGES / 1024, 256, 0, stream>>>(esrc, edst, rankb, offsets, csr);

    // 3 GIN layers: g = h @ W  (bufG, bf16);  h' = (1+eps)g + agg(g) + b  (d_out, f32)
    const float* h = feats;
    for (int l = 0; l < 3; l++) {
        gemm_k<<<(N_NODES + 63) / 64, 256, 0, stream>>>(h, Wm[l], bufG);
        agg_k<<<N_NODES / 4, 256, 0, stream>>>(bufG, offsets, csr, Bv[l], Ev[l], out);
        h = out;
    }
}